// Round 10
// baseline (227.185 us; speedup 1.0000x reference)
//
#include <hip/hip_runtime.h>
#include <hip/hip_bf16.h>
#include <math.h>

#define NNODES 20000
#define NEDGES 320000
#define SCAT_BLOCKS 1250
#define MBLK 313            // 64-row blocks per matrix

using f32x4 = __attribute__((ext_vector_type(4))) float;
using s16x8 = __attribute__((ext_vector_type(8))) short;
using u16x8 = __attribute__((ext_vector_type(8))) unsigned short;

__device__ __forceinline__ float bf2f(unsigned short u) {
    union { unsigned int i; float f; } c; c.i = ((unsigned int)u) << 16; return c.f;
}
__device__ __forceinline__ unsigned short f2bf(float f) {
    __hip_bfloat16 h = __float2bfloat16(f);
    return *reinterpret_cast<unsigned short*>(&h);
}
// cross-lane add via DPP quad_perm (VALU pipe -- no lgkmcnt interference)
template <int CTRL>
__device__ __forceinline__ float dpp_xadd(float x) {
    union { float f; int i; } a, b;
    a.f = x;
    b.i = __builtin_amdgcn_update_dpp(0, a.i, CTRL, 0xf, 0xf, true);
    return x + b.f;
}

// ---------------------------------------------------------------------------
// prep + hist + hcvt fused (disjoint gid ranges; counts pre-zeroed).
// Head-major col c = head*32+dim <-> original col n_old = dim*8+head.
// q weights/bias scaled by 32^-0.5 * log2(e) (exp -> exp2).
// Weight layout for coalesced in-loop B-fragment loads:
//   wt2[((mat*8 + k8)*256 + n)*32 + ko] , k = k8*32+ko:
//     mats 0-2: = W[k][n_old(n)]            (B-cols = head-major out cols)
//     mat  3  : = Wo[n_old(k)][n]           (contraction k is head-major)
// ---------------------------------------------------------------------------
__global__ __launch_bounds__(256) void prep_all_k(
    const float* __restrict__ Wq, const float* __restrict__ bq,
    const float* __restrict__ Wk, const float* __restrict__ bk,
    const float* __restrict__ Wv, const float* __restrict__ bv,
    const float* __restrict__ Wo, const int* __restrict__ rows,
    const float* __restrict__ h,
    unsigned short* __restrict__ wt2, float* __restrict__ bp,
    int* __restrict__ counts, unsigned short* __restrict__ hb)
{
    const int gid = blockIdx.x * 256 + threadIdx.x;
    const float SCQ = 0.17677669529663687f * 1.4426950408889634f;
    if (gid < 262144) {
        const int mat = gid >> 16, r = gid & 65535;
        if (mat < 3) {
            const int k = r >> 8, c = r & 255;
            const int n_old = ((c & 31) << 3) | (c >> 5);
            const float* W = (mat == 0) ? Wq : (mat == 1) ? Wk : Wv;
            float val = W[k * 256 + n_old];
            if (mat == 0) val *= SCQ;
            wt2[((mat * 8 + (k >> 5)) * 256 + c) * 32 + (k & 31)] = f2bf(val);
        } else {
            const int k = r & 255, n = r >> 8;   // k = head-major contraction idx
            const int n_old = ((k & 31) << 3) | (k >> 5);
            wt2[((24 + (k >> 5)) * 256 + n) * 32 + (k & 31)] = f2bf(Wo[n_old * 256 + n]);
        }
    } else if (gid < 262912) {
        const int idx = gid - 262144;
        const int mat = idx >> 8, c = idx & 255;
        const int n_old = ((c & 31) << 3) | (c >> 5);
        const float* b = (mat == 0) ? bq : (mat == 1) ? bk : bv;
        float val = b[n_old];
        if (mat == 0) val *= SCQ;
        bp[mat * 256 + c] = val;
    } else if (gid < 582912) {
        atomicAdd(&counts[rows[gid - 262912]], 1);
    } else {  // gid < 1,862,912 : h -> bf16, 4 elements each
        const int i = (gid - 582912) * 4;
        const float4 f = *reinterpret_cast<const float4*>(&h[i]);
        ushort4 u;
        u.x = f2bf(f.x); u.y = f2bf(f.y); u.z = f2bf(f.z); u.w = f2bf(f.w);
        *reinterpret_cast<ushort4*>(&hb[i]) = u;
    }
}

// ---------------------------------------------------------------------------
// single-pass exclusive scan: 1024 threads x 20 contiguous elements
// ---------------------------------------------------------------------------
__global__ __launch_bounds__(1024) void scan_k(const int* __restrict__ counts,
                                               int* __restrict__ row_start)
{
    __shared__ int wsum[16];
    const int t = threadIdx.x, lane = t & 63, w = t >> 6;
    const int base = t * 20;
    int c[20]; int s = 0;
    #pragma unroll
    for (int j = 0; j < 20; ++j) {
        const int idx = base + j;
        c[j] = (idx < NNODES) ? counts[idx] : 0;
        s += c[j];
    }
    int incl = s;
    #pragma unroll
    for (int off = 1; off < 64; off <<= 1) {
        const int y = __shfl_up(incl, off);
        if (lane >= off) incl += y;
    }
    if (lane == 63) wsum[w] = incl;
    __syncthreads();
    int prev = 0;
    for (int i = 0; i < w; ++i) prev += wsum[i];
    int run = prev + incl - s;
    if (t == 0) row_start[0] = 0;
    #pragma unroll
    for (int j = 0; j < 20; ++j) {
        const int idx = base + j;
        run += c[j];
        if (idx < NNODES) row_start[idx + 1] = run;
    }
}

// ---------------------------------------------------------------------------
// GEMM core: 64 rows x 256 cols per block, 4 waves (wave w = cols w*64..+63).
// A (64x256 bf16) staged in LDS once (1 barrier); K-loop is BARRIER-FREE:
// per k8: 4 coalesced 16B B-loads from wt2 (L2-hot) + 4 ds_read_b128 + 16 MFMA.
// ---------------------------------------------------------------------------
__device__ __forceinline__ void gemm_body(
    const unsigned short* __restrict__ Asrc,   // [rows][256] bf16, row-clamped
    const unsigned short* __restrict__ wt2, int mat, int bm,
    f32x4 (&acc)[4][4], unsigned short (&As)[64][264],
    int t, int lane)
{
    const int l15 = lane & 15, l4 = lane >> 4;
    const int w = t >> 6;
    const int wc = w * 64;
    {   // stage A once: thread t -> row t>>2, 64 shorts at (t&3)*64
        const int arow = t >> 2;
        const int coff = (t & 3) * 64;
        const int m0 = min(bm + arow, NNODES - 1);
        const unsigned short* pa = Asrc + m0 * 256 + coff;
        #pragma unroll
        for (int s = 0; s < 8; ++s)
            *(u16x8*)&As[arow][coff + s * 8] = *(const u16x8*)(pa + s * 8);
    }
    __syncthreads();

    #pragma unroll
    for (int i = 0; i < 4; ++i)
        #pragma unroll
        for (int j = 0; j < 4; ++j) acc[i][j] = (f32x4){0.f, 0.f, 0.f, 0.f};

    const unsigned short* bb = wt2 + (mat * 8) * 256 * 32 + l4 * 8;
    #pragma unroll
    for (int k8 = 0; k8 < 8; ++k8) {
        s16x8 b[4], a[4];
        #pragma unroll
        for (int j = 0; j < 4; ++j)
            b[j] = *(const s16x8*)(bb + (k8 * 256 + wc + j * 16 + l15) * 32);
        const int kk = k8 * 32 + l4 * 8;
        #pragma unroll
        for (int i = 0; i < 4; ++i)
            a[i] = *(const s16x8*)&As[i * 16 + l15][kk];
        #pragma unroll
        for (int i = 0; i < 4; ++i)
            #pragma unroll
            for (int j = 0; j < 4; ++j)
                acc[i][j] = __builtin_amdgcn_mfma_f32_16x16x32_bf16(a[i], b[j], acc[i][j], 0, 0, 0);
    }
}

// ---------------------------------------------------------------------------
// Merged scatter + QKV GEMM.
//   blocks [0, SCAT_BLOCKS): CSR scatter;  [SCAT_BLOCKS, +939): GEMM,
//   gb = blockIdx-SCAT_BLOCKS, mat = gb/313, bm = (gb%313)*64.
// Outputs: q_b, k_b, v_b separate [N][256] bf16 (coalesced writes, no RMW).
// ---------------------------------------------------------------------------
__global__ __launch_bounds__(256) void qkv_scatter_k(
    const unsigned short* __restrict__ hb,
    const unsigned short* __restrict__ wt2, const float* __restrict__ bp,
    const int* __restrict__ rows, const int* __restrict__ cols,
    const int* __restrict__ row_start, int* __restrict__ cursor,
    int* __restrict__ cols_sorted,
    unsigned short* __restrict__ qo, unsigned short* __restrict__ ko,
    unsigned short* __restrict__ vo)
{
    const int t = threadIdx.x;
    if (blockIdx.x < SCAT_BLOCKS) {
        const int i = blockIdx.x * 256 + t;
        if (i < NEDGES) {
            const int r = rows[i];
            const int pos = row_start[r] + atomicAdd(&cursor[r], 1);
            cols_sorted[pos] = cols[i];
        }
        return;
    }
    const int gb = blockIdx.x - SCAT_BLOCKS;
    const int mat = gb / MBLK;
    const int bm = (gb % MBLK) * 64;
    unsigned short* outp = (mat == 0) ? qo : (mat == 1) ? ko : vo;

    __shared__ __align__(16) unsigned short As[64][264];
    const int lane = t & 63;
    f32x4 acc[4][4];
    gemm_body(hb, wt2, mat, bm, acc, As, t, lane);

    const int l15 = lane & 15, l4 = lane >> 4;
    const int wc = (t >> 6) * 64;
    #pragma unroll
    for (int j = 0; j < 4; ++j) {
        const int n = wc + j * 16 + l15;
        const float bval = bp[mat * 256 + n];
        #pragma unroll
        for (int i = 0; i < 4; ++i) {
            #pragma unroll
            for (int r = 0; r < 4; ++r) {
                const int m = bm + i * 16 + l4 * 4 + r;
                if (m < NNODES) outp[m * 256 + n] = f2bf(acc[i][j][r] + bval);
            }
        }
    }
}

// ---------------------------------------------------------------------------
// Output projection: same barrier-free core, fp32 out + bo.
// ---------------------------------------------------------------------------
__global__ __launch_bounds__(256) void out_proj_k(
    const unsigned short* __restrict__ A,
    const unsigned short* __restrict__ wt2, const float* __restrict__ bo,
    float* __restrict__ C)
{
    const int t = threadIdx.x;
    const int bm = blockIdx.x * 64;

    __shared__ __align__(16) unsigned short As[64][264];
    const int lane = t & 63;
    f32x4 acc[4][4];
    gemm_body(A, wt2, 3, bm, acc, As, t, lane);

    const int l15 = lane & 15, l4 = lane >> 4;
    const int wc = (t >> 6) * 64;
    #pragma unroll
    for (int j = 0; j < 4; ++j) {
        const int n = wc + j * 16 + l15;
        const float bval = bo[n];
        #pragma unroll
        for (int i = 0; i < 4; ++i) {
            #pragma unroll
            for (int r = 0; r < 4; ++r) {
                const int m = bm + i * 16 + l4 * 4 + r;
                if (m < NNODES) C[m * 256 + n] = acc[i][j][r] + bval;
            }
        }
    }
}

// ---------------------------------------------------------------------------
// Fused SDDMM + softmax + SPMM. One wave per row; half-wave per edge.
// Lane w5: head w5>>2, dims (w5&3)*8..+7. Dot reduce = 2 DPP quad_perm adds.
// Col indices via scalar loads; 4-edge ping-pong. k/v in separate arrays
// (two 16B loads/edge/lane -- same line traffic as interleaved).
// ---------------------------------------------------------------------------
__global__ __launch_bounds__(256) void row_attn_k(
    const unsigned short* __restrict__ q, const unsigned short* __restrict__ kk_,
    const unsigned short* __restrict__ vv_,
    const int* __restrict__ row_start, const int* __restrict__ cols_sorted,
    unsigned short* __restrict__ ot)
{
    const int lane = threadIdx.x & 63;
    const int w5 = lane & 31;
    const int half = lane >> 5;
    const int row = __builtin_amdgcn_readfirstlane(blockIdx.x * 4 + (threadIdx.x >> 6));
    const int rs = row_start[row];
    const int re = row_start[row + 1];
    const int deg = re - rs;

    float qd[8];
    {
        const u16x8 qu = *reinterpret_cast<const u16x8*>(&q[row * 256 + w5 * 8]);
        #pragma unroll
        for (int d = 0; d < 8; ++d) qd[d] = bf2f(qu[d]);
    }
    float o[8] = {0.f, 0.f, 0.f, 0.f, 0.f, 0.f, 0.f, 0.f};
    float z = 0.f;
    const int* cp = cols_sorted + rs;

#define LP(K, V, base) do { \
    const int c0 = cp[min((base), deg - 1)]; \
    const int c1 = cp[min((base) + 1, deg - 1)]; \
    const int cn = half ? c1 : c0; \
    K = *reinterpret_cast<const u16x8*>(kk_ + cn * 256 + w5 * 8); \
    V = *reinterpret_cast<const u16x8*>(vv_ + cn * 256 + w5 * 8); \
} while (0)

#define CMP(K, V, base) do { \
    float pa_ = qd[0] * bf2f(K[0]); \
    float pb_ = qd[1] * bf2f(K[1]); \
    pa_ = fmaf(qd[2], bf2f(K[2]), pa_); \
    pb_ = fmaf(qd[3], bf2f(K[3]), pb_); \
    pa_ = fmaf(qd[4], bf2f(K[4]), pa_); \
    pb_ = fmaf(qd[5], bf2f(K[5]), pb_); \
    pa_ = fmaf(qd[6], bf2f(K[6]), pa_); \
    pb_ = fmaf(qd[7], bf2f(K[7]), pb_); \
    float p_ = pa_ + pb_; \
    p_ = dpp_xadd<0xB1>(p_); \
    p_ = dpp_xadd<0x4E>(p_); \
    const float e_ = ((base) + half < deg) ? exp2f(p_) : 0.f; \
    z += e_; \
    o[0] = fmaf(e_, bf2f(V[0]), o[0]); \
    o[1] = fmaf(e_, bf2f(V[1]), o[1]); \
    o[2] = fmaf(e_, bf2f(V[2]), o[2]); \
    o[3] = fmaf(e_, bf2f(V[3]), o[3]); \
    o[4] = fmaf(e_, bf2f(V[4]), o[4]); \
    o[5] = fmaf(e_, bf2f(V[5]), o[5]); \
    o[6] = fmaf(e_, bf2f(V[6]), o[6]); \
    o[7] = fmaf(e_, bf2f(V[7]), o[7]); \
} while (0)

    if (deg > 0) {
        u16x8 ak0, av0, ak1, av1, bk0, bv0, bk1, bv1;
        LP(ak0, av0, 0);
        LP(ak1, av1, 2);
        for (int i0 = 0; i0 < deg; i0 += 8) {
            const bool hb2 = (i0 + 4) < deg;
            if (hb2) { LP(bk0, bv0, i0 + 4); LP(bk1, bv1, i0 + 6); }
            CMP(ak0, av0, i0);
            CMP(ak1, av1, i0 + 2);
            if (i0 + 8 < deg) { LP(ak0, av0, i0 + 8); LP(ak1, av1, i0 + 10); }
            if (hb2) { CMP(bk0, bv0, i0 + 4); CMP(bk1, bv1, i0 + 6); }
        }
    }
#undef LP
#undef CMP

    z += __shfl_xor(z, 32);
    #pragma unroll
    for (int d = 0; d < 8; ++d) o[d] += __shfl_xor(o[d], 32);

    if (half == 0) {
        u16x8 r;
        if (deg > 0) {
            const float iz = 1.0f / z;
            #pragma unroll
            for (int d = 0; d < 8; ++d) r[d] = f2bf(o[d] * iz);
        } else {
            #pragma unroll
            for (int d = 0; d < 8; ++d) r[d] = 0;
        }
        *reinterpret_cast<u16x8*>(&ot[row * 256 + w5 * 8]) = r;
    }
}

// ---------------------------------------------------------------------------
extern "C" void kernel_launch(void* const* d_in, const int* in_sizes, int n_in,
                              void* d_out, int out_size, void* d_ws, size_t ws_size,
                              hipStream_t stream)
{
    const float* h  = (const float*)d_in[0];
    const float* Wq = (const float*)d_in[1];
    const float* bq = (const float*)d_in[2];
    const float* Wk = (const float*)d_in[3];
    const float* bk = (const float*)d_in[4];
    const float* Wv = (const float*)d_in[5];
    const float* bv = (const float*)d_in[6];
    const float* Wo = (const float*)d_in[7];
    const float* bo = (const float*)d_in[8];
    const int* rows = (const int*)d_in[9];
    const int* cols = (const int*)d_in[10];
    float* outp = (float*)d_out;

    // workspace layout (bytes), 16B-aligned; total ~54 MB
    char* ws = (char*)d_ws;
    unsigned short* q_b  = (unsigned short*)(ws + 0);          // 10,240,000
    unsigned short* k_b  = (unsigned short*)(ws + 10240000);   // 10,240,000
    unsigned short* v_b  = (unsigned short*)(ws + 20480000);   // 10,240,000
    unsigned short* ot_b = (unsigned short*)(ws + 30720000);   // 10,240,000
    unsigned short* h_b  = (unsigned short*)(ws + 40960000);   // 10,240,000
    unsigned short* wt2  = (unsigned short*)(ws + 51200000);   // 524,288
    float* bp            = (float*)(ws + 51724288);            // 3,072
    int* row_start       = (int*)(ws + 51727360);              // 80,004
    int* counts          = (int*)(ws + 51807488);              // 80,000
    int* cursor          = (int*)(ws + 51887488);              // 80,000
    int* cols_sorted     = (int*)(ws + 51967488);              // 1,280,000 + pad

    hipMemsetAsync(ws + 51807488, 0, 160000, stream);          // counts + cursor

    prep_all_k<<<7277, 256, 0, stream>>>(Wq, bq, Wk, bk, Wv, bv, Wo, rows, h,
                                         wt2, bp, counts, h_b);
    scan_k<<<1, 1024, 0, stream>>>(counts, row_start);
    qkv_scatter_k<<<SCAT_BLOCKS + 3 * MBLK, 256, 0, stream>>>(
        h_b, wt2, bp, rows, cols, row_start, cursor, cols_sorted, q_b, k_b, v_b);
    row_attn_k<<<5000, 256, 0, stream>>>(q_b, k_b, v_b, row_start, cols_sorted, ot_b);
    out_proj_k<<<MBLK, 256, 0, stream>>>(ot_b, wt2, bo, outp);
}

// Round 11
// 215.264 us; speedup vs baseline: 1.0554x; 1.0554x over previous
//
#include <hip/hip_runtime.h>
#include <hip/hip_bf16.h>
#include <math.h>

#define NNODES 20000
#define NEDGES 320000
#define SCAT_BLOCKS 1250
#define MBLK 313            // 64-row blocks per matrix

using f32x4 = __attribute__((ext_vector_type(4))) float;
using s16x8 = __attribute__((ext_vector_type(8))) short;
using u16x8 = __attribute__((ext_vector_type(8))) unsigned short;

__device__ __forceinline__ float bf2f(unsigned short u) {
    union { unsigned int i; float f; } c; c.i = ((unsigned int)u) << 16; return c.f;
}
__device__ __forceinline__ unsigned short f2bf(float f) {
    __hip_bfloat16 h = __float2bfloat16(f);
    return *reinterpret_cast<unsigned short*>(&h);
}
// cross-lane add via DPP quad_perm (VALU pipe -- no lgkmcnt interference)
template <int CTRL>
__device__ __forceinline__ float dpp_xadd(float x) {
    union { float f; int i; } a, b;
    a.f = x;
    b.i = __builtin_amdgcn_update_dpp(0, a.i, CTRL, 0xf, 0xf, true);
    return x + b.f;
}

// ---------------------------------------------------------------------------
// prep + hist + hcvt fused (disjoint gid ranges; counts pre-zeroed).
// Head-major col c = head*32+dim <-> original col n_old = dim*8+head.
// q weights/bias scaled by 32^-0.5 * log2(e) (exp -> exp2).
//   mats 0-2: wt[mat][c][k] = W[k][n_old(c)]   (B rows = head-major out cols)
//   mat  3  : wt[3][n][c]   = Wo[n_old(c)][n]  (contraction idx c head-major)
// ---------------------------------------------------------------------------
__global__ __launch_bounds__(256) void prep_all_k(
    const float* __restrict__ Wq, const float* __restrict__ bq,
    const float* __restrict__ Wk, const float* __restrict__ bk,
    const float* __restrict__ Wv, const float* __restrict__ bv,
    const float* __restrict__ Wo, const int* __restrict__ rows,
    const float* __restrict__ h,
    unsigned short* __restrict__ wt, float* __restrict__ bp,
    int* __restrict__ counts, unsigned short* __restrict__ hb)
{
    const int gid = blockIdx.x * 256 + threadIdx.x;
    const float SCQ = 0.17677669529663687f * 1.4426950408889634f;
    if (gid < 262144) {
        const int mat = gid >> 16, r = gid & 65535;
        if (mat < 3) {
            const int k = r >> 8, c = r & 255;
            const int n_old = ((c & 31) << 3) | (c >> 5);
            const float* W = (mat == 0) ? Wq : (mat == 1) ? Wk : Wv;
            float val = W[k * 256 + n_old];
            if (mat == 0) val *= SCQ;
            wt[mat * 65536 + c * 256 + k] = f2bf(val);
        } else {
            const int c = r >> 8, n = r & 255;
            const int n_old = ((c & 31) << 3) | (c >> 5);
            wt[3 * 65536 + n * 256 + c] = f2bf(Wo[n_old * 256 + n]);
        }
    } else if (gid < 262912) {
        const int idx = gid - 262144;
        const int mat = idx >> 8, c = idx & 255;
        const int n_old = ((c & 31) << 3) | (c >> 5);
        const float* b = (mat == 0) ? bq : (mat == 1) ? bk : bv;
        float val = b[n_old];
        if (mat == 0) val *= SCQ;
        bp[mat * 256 + c] = val;
    } else if (gid < 582912) {
        atomicAdd(&counts[rows[gid - 262912]], 1);
    } else {  // gid < 1,862,912 : h -> bf16, 4 elements each
        const int i = (gid - 582912) * 4;
        const float4 f = *reinterpret_cast<const float4*>(&h[i]);
        ushort4 u;
        u.x = f2bf(f.x); u.y = f2bf(f.y); u.z = f2bf(f.z); u.w = f2bf(f.w);
        *reinterpret_cast<ushort4*>(&hb[i]) = u;
    }
}

// ---------------------------------------------------------------------------
// single-pass exclusive scan: 1024 threads x 20 contiguous elements
// ---------------------------------------------------------------------------
__global__ __launch_bounds__(1024) void scan_k(const int* __restrict__ counts,
                                               int* __restrict__ row_start)
{
    __shared__ int wsum[16];
    const int t = threadIdx.x, lane = t & 63, w = t >> 6;
    const int base = t * 20;
    int c[20]; int s = 0;
    #pragma unroll
    for (int j = 0; j < 20; ++j) {
        const int idx = base + j;
        c[j] = (idx < NNODES) ? counts[idx] : 0;
        s += c[j];
    }
    int incl = s;
    #pragma unroll
    for (int off = 1; off < 64; off <<= 1) {
        const int y = __shfl_up(incl, off);
        if (lane >= off) incl += y;
    }
    if (lane == 63) wsum[w] = incl;
    __syncthreads();
    int prev = 0;
    for (int i = 0; i < w; ++i) prev += wsum[i];
    int run = prev + incl - s;
    if (t == 0) row_start[0] = 0;
    #pragma unroll
    for (int j = 0; j < 20; ++j) {
        const int idx = base + j;
        run += c[j];
        if (idx < NNODES) row_start[idx + 1] = run;
    }
}

// ---------------------------------------------------------------------------
// Merged scatter + QKV GEMM (R7 body: LDS-staged A+B, 64x128 tile, BK=32,
// 4 waves 2Mx2N, reg-prefetch of next K-tile) + NEW LDS-bounce epilogue for
// full-sector coalesced bf16 output writes.
//   blocks [0, SCAT_BLOCKS): CSR scatter; [SCAT_BLOCKS, +1878): GEMM,
//   gb -> bm=(gb%313)*64, y=gb/313, mat=y>>1, bn=(y&1)*128.
// smem aliasing: GEMM uses As(64x40)+Bs(128x40) = 7680 shorts;
// epilogue reuses smem as 64x132 C-tile (8448 shorts = 16,896 B).
// ---------------------------------------------------------------------------
__global__ __launch_bounds__(256) void qkv_scatter_k(
    const unsigned short* __restrict__ hb,
    const unsigned short* __restrict__ wt, const float* __restrict__ bp,
    const int* __restrict__ rows, const int* __restrict__ cols,
    const int* __restrict__ row_start, int* __restrict__ cursor,
    int* __restrict__ cols_sorted,
    unsigned short* __restrict__ qo, unsigned short* __restrict__ ko,
    unsigned short* __restrict__ vo)
{
    const int t = threadIdx.x;
    if (blockIdx.x < SCAT_BLOCKS) {
        const int i = blockIdx.x * 256 + t;
        if (i < NEDGES) {
            const int r = rows[i];
            const int pos = row_start[r] + atomicAdd(&cursor[r], 1);
            cols_sorted[pos] = cols[i];
        }
        return;
    }
    const int gb = blockIdx.x - SCAT_BLOCKS;
    const int bm = (gb % MBLK) * 64;
    const int y = gb / MBLK;
    const int mat = y >> 1;
    const int bn = (y & 1) * 128;
    const unsigned short* W = wt + mat * 65536;
    unsigned short* outp = (mat == 0) ? qo : (mat == 1) ? ko : vo;

    __shared__ __align__(16) unsigned short smem[8448];
#define AS(r, c) smem[(r) * 40 + (c)]
#define BS(r, c) smem[2560 + (r) * 40 + (c)]

    const int lane = t & 63, w = t >> 6;
    const int wr = (w >> 1) * 32, wc = (w & 1) * 64;
    const int l15 = lane & 15, l4 = lane >> 4;

    f32x4 acc[2][4];
    #pragma unroll
    for (int i = 0; i < 2; ++i)
        #pragma unroll
        for (int j = 0; j < 4; ++j) acc[i][j] = (f32x4){0.f, 0.f, 0.f, 0.f};

    const int arow = t >> 2, koff = (t & 3) * 8;
    const int m0 = min(bm + arow, NNODES - 1);
    const unsigned short* pa  = hb + m0 * 256 + koff;
    const unsigned short* pb0 = W + (bn + arow) * 256 + koff;
    const unsigned short* pb1 = W + (bn + arow + 64) * 256 + koff;

    u16x8 ra  = *(const u16x8*)(pa);
    u16x8 rb0 = *(const u16x8*)(pb0);
    u16x8 rb1 = *(const u16x8*)(pb1);

    #pragma unroll
    for (int kt = 0; kt < 8; ++kt) {
        __syncthreads();              // prev iteration's frag reads done
        *(u16x8*)&AS(arow, koff)      = ra;
        *(u16x8*)&BS(arow, koff)      = rb0;
        *(u16x8*)&BS(arow + 64, koff) = rb1;
        __syncthreads();
        if (kt < 7) {                 // issue next-tile loads before MFMAs
            const int k0 = (kt + 1) * 32;
            ra  = *(const u16x8*)(pa + k0);
            rb0 = *(const u16x8*)(pb0 + k0);
            rb1 = *(const u16x8*)(pb1 + k0);
        }
        s16x8 a[2], b[4];
        const int kk = l4 * 8;
        #pragma unroll
        for (int i = 0; i < 2; ++i)
            a[i] = *(const s16x8*)&AS(wr + i * 16 + l15, kk);
        #pragma unroll
        for (int j = 0; j < 4; ++j)
            b[j] = *(const s16x8*)&BS(wc + j * 16 + l15, kk);
        #pragma unroll
        for (int i = 0; i < 2; ++i)
            #pragma unroll
            for (int j = 0; j < 4; ++j)
                acc[i][j] = __builtin_amdgcn_mfma_f32_16x16x32_bf16(a[i], b[j], acc[i][j], 0, 0, 0);
    }
#undef AS
#undef BS

    // ---- LDS-bounce epilogue: stage C tile (64x132 stride), then coalesced
    float bv4[4];
    #pragma unroll
    for (int j = 0; j < 4; ++j) bv4[j] = bp[mat * 256 + bn + wc + j * 16 + l15];
    __syncthreads();                  // all frag reads done before overwrite
    #pragma unroll
    for (int i = 0; i < 2; ++i)
        #pragma unroll
        for (int r = 0; r < 4; ++r) {
            const int ml = wr + i * 16 + l4 * 4 + r;
            #pragma unroll
            for (int j = 0; j < 4; ++j)
                smem[ml * 132 + wc + j * 16 + l15] = f2bf(acc[i][j][r] + bv4[j]);
        }
    __syncthreads();
    {
        const int orow = t >> 2, ocol = (t & 3) * 32;
        const int m = bm + orow;
        if (m < NNODES) {
            unsigned short* dst = outp + m * 256 + bn + ocol;
            const unsigned short* src = &smem[orow * 132 + ocol];
            #pragma unroll
            for (int s = 0; s < 4; ++s)
                *(u16x8*)(dst + s * 8) = *(const u16x8*)(src + s * 8);
        }
    }
}

// ---------------------------------------------------------------------------
// Output projection: R7 body, fp32 direct writes (already sector-aligned).
// ---------------------------------------------------------------------------
__global__ __launch_bounds__(256) void out_mfma_k(
    const unsigned short* __restrict__ A,
    const unsigned short* __restrict__ wt, const float* __restrict__ bo,
    float* __restrict__ C)
{
    const int bm = blockIdx.x * 64;
    const int bn = blockIdx.y * 128;
    const unsigned short* W = wt + 3 * 65536;

    __shared__ __align__(16) unsigned short As[64][40];
    __shared__ __align__(16) unsigned short Bs[128][40];

    const int t = threadIdx.x;
    const int lane = t & 63, w = t >> 6;
    const int wr = (w >> 1) * 32, wc = (w & 1) * 64;
    const int l15 = lane & 15, l4 = lane >> 4;

    f32x4 acc[2][4];
    #pragma unroll
    for (int i = 0; i < 2; ++i)
        #pragma unroll
        for (int j = 0; j < 4; ++j) acc[i][j] = (f32x4){0.f, 0.f, 0.f, 0.f};

    const int arow = t >> 2, koff = (t & 3) * 8;
    const int m0 = min(bm + arow, NNODES - 1);
    const unsigned short* pa  = A + m0 * 256 + koff;
    const unsigned short* pb0 = W + (bn + arow) * 256 + koff;
    const unsigned short* pb1 = W + (bn + arow + 64) * 256 + koff;

    u16x8 ra  = *(const u16x8*)(pa);
    u16x8 rb0 = *(const u16x8*)(pb0);
    u16x8 rb1 = *(const u16x8*)(pb1);

    #pragma unroll
    for (int kt = 0; kt < 8; ++kt) {
        __syncthreads();
        *(u16x8*)&As[arow][koff]      = ra;
        *(u16x8*)&Bs[arow][koff]      = rb0;
        *(u16x8*)&Bs[arow + 64][koff] = rb1;
        __syncthreads();
        if (kt < 7) {
            const int k0 = (kt + 1) * 32;
            ra  = *(const u16x8*)(pa + k0);
            rb0 = *(const u16x8*)(pb0 + k0);
            rb1 = *(const u16x8*)(pb1 + k0);
        }
        s16x8 a[2], b[4];
        const int kk = l4 * 8;
        #pragma unroll
        for (int i = 0; i < 2; ++i)
            a[i] = *(const s16x8*)&As[wr + i * 16 + l15][kk];
        #pragma unroll
        for (int j = 0; j < 4; ++j)
            b[j] = *(const s16x8*)&Bs[wc + j * 16 + l15][kk];
        #pragma unroll
        for (int i = 0; i < 2; ++i)
            #pragma unroll
            for (int j = 0; j < 4; ++j)
                acc[i][j] = __builtin_amdgcn_mfma_f32_16x16x32_bf16(a[i], b[j], acc[i][j], 0, 0, 0);
    }
    #pragma unroll
    for (int i = 0; i < 2; ++i)
        #pragma unroll
        for (int r = 0; r < 4; ++r) {
            const int m = bm + wr + i * 16 + l4 * 4 + r;
            if (m >= NNODES) continue;
            #pragma unroll
            for (int j = 0; j < 4; ++j) {
                const int n = bn + wc + j * 16 + l15;
                C[m * 256 + n] = acc[i][j][r] + bo[n];
            }
        }
}

// ---------------------------------------------------------------------------
// Fused SDDMM + softmax + SPMM. One wave per row; half-wave per edge.
// Lane w5: head w5>>2, dims (w5&3)*8..+7. Dot reduce = 2 DPP quad_perm adds.
// Col indices via scalar loads; 4-edge ping-pong. (unchanged)
// ---------------------------------------------------------------------------
__global__ __launch_bounds__(256) void row_attn_k(
    const unsigned short* __restrict__ q, const unsigned short* __restrict__ kk_,
    const unsigned short* __restrict__ vv_,
    const int* __restrict__ row_start, const int* __restrict__ cols_sorted,
    unsigned short* __restrict__ ot)
{
    const int lane = threadIdx.x & 63;
    const int w5 = lane & 31;
    const int half = lane >> 5;
    const int row = __builtin_amdgcn_readfirstlane(blockIdx.x * 4 + (threadIdx.x >> 6));
    const int rs = row_start[row];
    const int re = row_start[row + 1];
    const int deg = re - rs;

    float qd[8];
    {
        const u16x8 qu = *reinterpret_cast<const u16x8*>(&q[row * 256 + w5 * 8]);
        #pragma unroll
        for (int d = 0; d < 8; ++d) qd[d] = bf2f(qu[d]);
    }
    float o[8] = {0.f, 0.f, 0.f, 0.f, 0.f, 0.f, 0.f, 0.f};
    float z = 0.f;
    const int* cp = cols_sorted + rs;

#define LP(K, V, base) do { \
    const int c0 = cp[min((base), deg - 1)]; \
    const int c1 = cp[min((base) + 1, deg - 1)]; \
    const int cn = half ? c1 : c0; \
    K = *reinterpret_cast<const u16x8*>(kk_ + cn * 256 + w5 * 8); \
    V = *reinterpret_cast<const u16x8*>(vv_ + cn * 256 + w5 * 8); \
} while (0)

#define CMP(K, V, base) do { \
    float pa_ = qd[0] * bf2f(K[0]); \
    float pb_ = qd[1] * bf2f(K[1]); \
    pa_ = fmaf(qd[2], bf2f(K[2]), pa_); \
    pb_ = fmaf(qd[3], bf2f(K[3]), pb_); \
    pa_ = fmaf(qd[4], bf2f(K[4]), pa_); \
    pb_ = fmaf(qd[5], bf2f(K[5]), pb_); \
    pa_ = fmaf(qd[6], bf2f(K[6]), pa_); \
    pb_ = fmaf(qd[7], bf2f(K[7]), pb_); \
    float p_ = pa_ + pb_; \
    p_ = dpp_xadd<0xB1>(p_); \
    p_ = dpp_xadd<0x4E>(p_); \
    const float e_ = ((base) + half < deg) ? exp2f(p_) : 0.f; \
    z += e_; \
    o[0] = fmaf(e_, bf2f(V[0]), o[0]); \
    o[1] = fmaf(e_, bf2f(V[1]), o[1]); \
    o[2] = fmaf(e_, bf2f(V[2]), o[2]); \
    o[3] = fmaf(e_, bf2f(V[3]), o[3]); \
    o[4] = fmaf(e_, bf2f(V[4]), o[4]); \
    o[5] = fmaf(e_, bf2f(V[5]), o[5]); \
    o[6] = fmaf(e_, bf2f(V[6]), o[6]); \
    o[7] = fmaf(e_, bf2f(V[7]), o[7]); \
} while (0)

    if (deg > 0) {
        u16x8 ak0, av0, ak1, av1, bk0, bv0, bk1, bv1;
        LP(ak0, av0, 0);
        LP(ak1, av1, 2);
        for (int i0 = 0; i0 < deg; i0 += 8) {
            const bool hb2 = (i0 + 4) < deg;
            if (hb2) { LP(bk0, bv0, i0 + 4); LP(bk1, bv1, i0 + 6); }
            CMP(ak0, av0, i0);
            CMP(ak1, av1, i0 + 2);
            if (i0 + 8 < deg) { LP(ak0, av0, i0 + 8); LP(ak1, av1, i0 + 10); }
            if (hb2) { CMP(bk0, bv0, i0 + 4); CMP(bk1, bv1, i0 + 6); }
        }
    }
#undef LP
#undef CMP

    z += __shfl_xor(z, 32);
    #pragma unroll
    for (int d = 0; d < 8; ++d) o[d] += __shfl_xor(o[d], 32);

    if (half == 0) {
        u16x8 r;
        if (deg > 0) {
            const float iz = 1.0f / z;
            #pragma unroll
            for (int d = 0; d < 8; ++d) r[d] = f2bf(o[d] * iz);
        } else {
            #pragma unroll
            for (int d = 0; d < 8; ++d) r[d] = 0;
        }
        *reinterpret_cast<u16x8*>(&ot[row * 256 + w5 * 8]) = r;
    }
}

// ---------------------------------------------------------------------------
extern "C" void kernel_launch(void* const* d_in, const int* in_sizes, int n_in,
                              void* d_out, int out_size, void* d_ws, size_t ws_size,
                              hipStream_t stream)
{
    const float* h  = (const float*)d_in[0];
    const float* Wq = (const float*)d_in[1];
    const float* bq = (const float*)d_in[2];
    const float* Wk = (const float*)d_in[3];
    const float* bk = (const float*)d_in[4];
    const float* Wv = (const float*)d_in[5];
    const float* bv = (const float*)d_in[6];
    const float* Wo = (const float*)d_in[7];
    const float* bo = (const float*)d_in[8];
    const int* rows = (const int*)d_in[9];
    const int* cols = (const int*)d_in[10];
    float* outp = (float*)d_out;

    // workspace layout (bytes), 16B-aligned; total ~54 MB
    char* ws = (char*)d_ws;
    unsigned short* q_b  = (unsigned short*)(ws + 0);          // 10,240,000
    unsigned short* k_b  = (unsigned short*)(ws + 10240000);   // 10,240,000
    unsigned short* v_b  = (unsigned short*)(ws + 20480000);   // 10,240,000
    unsigned short* ot_b = (unsigned short*)(ws + 30720000);   // 10,240,000
    unsigned short* h_b  = (unsigned short*)(ws + 40960000);   // 10,240,000
    unsigned short* wt   = (unsigned short*)(ws + 51200000);   // 524,288
    float* bp            = (float*)(ws + 51724288);            // 3,072
    int* row_start       = (int*)(ws + 51727360);              // 80,004
    int* counts          = (int*)(ws + 51807488);              // 80,000
    int* cursor          = (int*)(ws + 51887488);              // 80,000
    int* cols_sorted     = (int*)(ws + 51967488);              // 1,280,000 + pad

    hipMemsetAsync(ws + 51807488, 0, 160000, stream);          // counts + cursor

    prep_all_k<<<7277, 256, 0, stream>>>(Wq, bq, Wk, bk, Wv, bv, Wo, rows, h,
                                         wt, bp, counts, h_b);
    scan_k<<<1, 1024, 0, stream>>>(counts, row_start);
    qkv_scatter_k<<<SCAT_BLOCKS + 6 * MBLK, 256, 0, stream>>>(
        h_b, wt, bp, rows, cols, row_start, cursor, cols_sorted, q_b, k_b, v_b);
    row_attn_k<<<5000, 256, 0, stream>>>(q_b, k_b, v_b, row_start, cols_sorted, ot_b);
    out_mfma_k<<<dim3(313, 2), 256, 0, stream>>>(ot_b, wt, bo, outp);
}

// Round 12
// 208.116 us; speedup vs baseline: 1.0916x; 1.0343x over previous
//
#include <hip/hip_runtime.h>
#include <hip/hip_bf16.h>
#include <math.h>

#define NNODES 20000
#define NEDGES 320000
#define SCAT_BLOCKS 1250
#define MBLK 313            // 64-row blocks per matrix

using f32x4 = __attribute__((ext_vector_type(4))) float;
using s16x8 = __attribute__((ext_vector_type(8))) short;
using u16x8 = __attribute__((ext_vector_type(8))) unsigned short;

__device__ __forceinline__ float bf2f(unsigned short u) {
    union { unsigned int i; float f; } c; c.i = ((unsigned int)u) << 16; return c.f;
}
__device__ __forceinline__ unsigned short f2bf(float f) {
    __hip_bfloat16 h = __float2bfloat16(f);
    return *reinterpret_cast<unsigned short*>(&h);
}
// cross-lane add via DPP quad_perm (VALU pipe -- no lgkmcnt interference)
template <int CTRL>
__device__ __forceinline__ float dpp_xadd(float x) {
    union { float f; int i; } a, b;
    a.f = x;
    b.i = __builtin_amdgcn_update_dpp(0, a.i, CTRL, 0xf, 0xf, true);
    return x + b.f;
}

// ---------------------------------------------------------------------------
// prep + hist (disjoint gid ranges; counts pre-zeroed). 2277 blocks exactly.
// Head-major col c = head*32+dim <-> original col n_old = dim*8+head.
// q weights/bias scaled by 32^-0.5 * log2(e) (exp -> exp2).
//   mats 0-2: wt[mat][c][k] = W[k][n_old(c)]
//   mat  3  : wt[3][n][c]   = Wo[n_old(c)][n]
// ---------------------------------------------------------------------------
__global__ __launch_bounds__(256) void prep_all_k(
    const float* __restrict__ Wq, const float* __restrict__ bq,
    const float* __restrict__ Wk, const float* __restrict__ bk,
    const float* __restrict__ Wv, const float* __restrict__ bv,
    const float* __restrict__ Wo, const int* __restrict__ rows,
    unsigned short* __restrict__ wt, float* __restrict__ bp,
    int* __restrict__ counts)
{
    const int gid = blockIdx.x * 256 + threadIdx.x;
    const float SCQ = 0.17677669529663687f * 1.4426950408889634f;
    if (gid < 262144) {
        const int mat = gid >> 16, r = gid & 65535;
        if (mat < 3) {
            const int k = r >> 8, c = r & 255;
            const int n_old = ((c & 31) << 3) | (c >> 5);
            const float* W = (mat == 0) ? Wq : (mat == 1) ? Wk : Wv;
            float val = W[k * 256 + n_old];
            if (mat == 0) val *= SCQ;
            wt[mat * 65536 + c * 256 + k] = f2bf(val);
        } else {
            const int c = r >> 8, n = r & 255;
            const int n_old = ((c & 31) << 3) | (c >> 5);
            wt[3 * 65536 + n * 256 + c] = f2bf(Wo[n_old * 256 + n]);
        }
    } else if (gid < 262912) {
        const int idx = gid - 262144;
        const int mat = idx >> 8, c = idx & 255;
        const int n_old = ((c & 31) << 3) | (c >> 5);
        const float* b = (mat == 0) ? bq : (mat == 1) ? bk : bv;
        float val = b[n_old];
        if (mat == 0) val *= SCQ;
        bp[mat * 256 + c] = val;
    } else if (gid < 582912) {
        atomicAdd(&counts[rows[gid - 262912]], 1);
    }
}

// ---------------------------------------------------------------------------
// scan (block 0) + hcvt (blocks 1..1250) in one dispatch: scan's serial
// latency hides under hcvt's bandwidth work.
// ---------------------------------------------------------------------------
__global__ __launch_bounds__(1024) void scan_hcvt_k(
    const int* __restrict__ counts, int* __restrict__ row_start,
    const float* __restrict__ h, unsigned short* __restrict__ hb)
{
    if (blockIdx.x == 0) {
        __shared__ int wsum[16];
        const int t = threadIdx.x, lane = t & 63, w = t >> 6;
        const int base = t * 20;
        int c[20]; int s = 0;
        #pragma unroll
        for (int j = 0; j < 20; ++j) {
            const int idx = base + j;
            c[j] = (idx < NNODES) ? counts[idx] : 0;
            s += c[j];
        }
        int incl = s;
        #pragma unroll
        for (int off = 1; off < 64; off <<= 1) {
            const int y = __shfl_up(incl, off);
            if (lane >= off) incl += y;
        }
        if (lane == 63) wsum[w] = incl;
        __syncthreads();
        int prev = 0;
        for (int i = 0; i < w; ++i) prev += wsum[i];
        int run = prev + incl - s;
        if (t == 0) row_start[0] = 0;
        #pragma unroll
        for (int j = 0; j < 20; ++j) {
            const int idx = base + j;
            run += c[j];
            if (idx < NNODES) row_start[idx + 1] = run;
        }
    } else {
        const int i = ((blockIdx.x - 1) * 1024 + threadIdx.x) * 4;
        const float4 f = *reinterpret_cast<const float4*>(&h[i]);
        ushort4 u;
        u.x = f2bf(f.x); u.y = f2bf(f.y); u.z = f2bf(f.z); u.w = f2bf(f.w);
        *reinterpret_cast<ushort4*>(&hb[i]) = u;
    }
}

// ---------------------------------------------------------------------------
// Merged scatter + QKV GEMM (R11 body + 2-deep register prefetch) with
// LDS-bounce epilogue for full-sector coalesced bf16 writes.
//   blocks [0, SCAT_BLOCKS): CSR scatter; [SCAT_BLOCKS, +1878): GEMM,
//   gb -> bm=(gb%313)*64, y=gb/313, mat=y>>1, bn=(y&1)*128.
// ---------------------------------------------------------------------------
__global__ __launch_bounds__(256) void qkv_scatter_k(
    const unsigned short* __restrict__ hb,
    const unsigned short* __restrict__ wt, const float* __restrict__ bp,
    const int* __restrict__ rows, const int* __restrict__ cols,
    const int* __restrict__ row_start, int* __restrict__ cursor,
    int* __restrict__ cols_sorted,
    unsigned short* __restrict__ qo, unsigned short* __restrict__ ko,
    unsigned short* __restrict__ vo)
{
    const int t = threadIdx.x;
    if (blockIdx.x < SCAT_BLOCKS) {
        const int i = blockIdx.x * 256 + t;
        if (i < NEDGES) {
            const int r = rows[i];
            const int pos = row_start[r] + atomicAdd(&cursor[r], 1);
            cols_sorted[pos] = cols[i];
        }
        return;
    }
    const int gb = blockIdx.x - SCAT_BLOCKS;
    const int bm = (gb % MBLK) * 64;
    const int y = gb / MBLK;
    const int mat = y >> 1;
    const int bn = (y & 1) * 128;
    const unsigned short* W = wt + mat * 65536;
    unsigned short* outp = (mat == 0) ? qo : (mat == 1) ? ko : vo;

    __shared__ __align__(16) unsigned short smem[8448];
#define AS(r, c) smem[(r) * 40 + (c)]
#define BS(r, c) smem[2560 + (r) * 40 + (c)]

    const int lane = t & 63, w = t >> 6;
    const int wr = (w >> 1) * 32, wc = (w & 1) * 64;
    const int l15 = lane & 15, l4 = lane >> 4;

    f32x4 acc[2][4];
    #pragma unroll
    for (int i = 0; i < 2; ++i)
        #pragma unroll
        for (int j = 0; j < 4; ++j) acc[i][j] = (f32x4){0.f, 0.f, 0.f, 0.f};

    const int arow = t >> 2, koff = (t & 3) * 8;
    const int m0 = min(bm + arow, NNODES - 1);
    const unsigned short* pa  = hb + m0 * 256 + koff;
    const unsigned short* pb0 = W + (bn + arow) * 256 + koff;
    const unsigned short* pb1 = W + (bn + arow + 64) * 256 + koff;

    // 2-deep register pipeline: cur (write now), nxt (write next iter)
    u16x8 ra_c  = *(const u16x8*)(pa);
    u16x8 rb0_c = *(const u16x8*)(pb0);
    u16x8 rb1_c = *(const u16x8*)(pb1);
    u16x8 ra_n  = *(const u16x8*)(pa + 32);
    u16x8 rb0_n = *(const u16x8*)(pb0 + 32);
    u16x8 rb1_n = *(const u16x8*)(pb1 + 32);

    #pragma unroll
    for (int kt = 0; kt < 8; ++kt) {
        __syncthreads();              // prev iteration's frag reads done
        *(u16x8*)&AS(arow, koff)      = ra_c;
        *(u16x8*)&BS(arow, koff)      = rb0_c;
        *(u16x8*)&BS(arow + 64, koff) = rb1_c;
        __syncthreads();
        ra_c = ra_n; rb0_c = rb0_n; rb1_c = rb1_n;   // renamed away by unroll
        if (kt < 6) {                 // load tile kt+2 (2 barrier periods away)
            const int k0 = (kt + 2) * 32;
            ra_n  = *(const u16x8*)(pa + k0);
            rb0_n = *(const u16x8*)(pb0 + k0);
            rb1_n = *(const u16x8*)(pb1 + k0);
        }
        s16x8 a[2], b[4];
        const int kk = l4 * 8;
        #pragma unroll
        for (int i = 0; i < 2; ++i)
            a[i] = *(const s16x8*)&AS(wr + i * 16 + l15, kk);
        #pragma unroll
        for (int j = 0; j < 4; ++j)
            b[j] = *(const s16x8*)&BS(wc + j * 16 + l15, kk);
        #pragma unroll
        for (int i = 0; i < 2; ++i)
            #pragma unroll
            for (int j = 0; j < 4; ++j)
                acc[i][j] = __builtin_amdgcn_mfma_f32_16x16x32_bf16(a[i], b[j], acc[i][j], 0, 0, 0);
    }
#undef AS
#undef BS

    // ---- LDS-bounce epilogue: stage C tile (64x132 stride), then coalesced
    float bv4[4];
    #pragma unroll
    for (int j = 0; j < 4; ++j) bv4[j] = bp[mat * 256 + bn + wc + j * 16 + l15];
    __syncthreads();                  // all frag reads done before overwrite
    #pragma unroll
    for (int i = 0; i < 2; ++i)
        #pragma unroll
        for (int r = 0; r < 4; ++r) {
            const int ml = wr + i * 16 + l4 * 4 + r;
            #pragma unroll
            for (int j = 0; j < 4; ++j)
                smem[ml * 132 + wc + j * 16 + l15] = f2bf(acc[i][j][r] + bv4[j]);
        }
    __syncthreads();
    {
        const int orow = t >> 2, ocol = (t & 3) * 32;
        const int m = bm + orow;
        if (m < NNODES) {
            unsigned short* dst = outp + m * 256 + bn + ocol;
            const unsigned short* src = &smem[orow * 132 + ocol];
            #pragma unroll
            for (int s = 0; s < 4; ++s)
                *(u16x8*)(dst + s * 8) = *(const u16x8*)(src + s * 8);
        }
    }
}

// ---------------------------------------------------------------------------
// Output projection: R11 body + 2-deep prefetch, fp32 direct writes.
// ---------------------------------------------------------------------------
__global__ __launch_bounds__(256) void out_mfma_k(
    const unsigned short* __restrict__ A,
    const unsigned short* __restrict__ wt, const float* __restrict__ bo,
    float* __restrict__ C)
{
    const int bm = blockIdx.x * 64;
    const int bn = blockIdx.y * 128;
    const unsigned short* W = wt + 3 * 65536;

    __shared__ __align__(16) unsigned short As[64][40];
    __shared__ __align__(16) unsigned short Bs[128][40];

    const int t = threadIdx.x;
    const int lane = t & 63, w = t >> 6;
    const int wr = (w >> 1) * 32, wc = (w & 1) * 64;
    const int l15 = lane & 15, l4 = lane >> 4;

    f32x4 acc[2][4];
    #pragma unroll
    for (int i = 0; i < 2; ++i)
        #pragma unroll
        for (int j = 0; j < 4; ++j) acc[i][j] = (f32x4){0.f, 0.f, 0.f, 0.f};

    const int arow = t >> 2, koff = (t & 3) * 8;
    const int m0 = min(bm + arow, NNODES - 1);
    const unsigned short* pa  = A + m0 * 256 + koff;
    const unsigned short* pb0 = W + (bn + arow) * 256 + koff;
    const unsigned short* pb1 = W + (bn + arow + 64) * 256 + koff;

    u16x8 ra_c  = *(const u16x8*)(pa);
    u16x8 rb0_c = *(const u16x8*)(pb0);
    u16x8 rb1_c = *(const u16x8*)(pb1);
    u16x8 ra_n  = *(const u16x8*)(pa + 32);
    u16x8 rb0_n = *(const u16x8*)(pb0 + 32);
    u16x8 rb1_n = *(const u16x8*)(pb1 + 32);

    #pragma unroll
    for (int kt = 0; kt < 8; ++kt) {
        __syncthreads();
        *(u16x8*)&As[arow][koff]      = ra_c;
        *(u16x8*)&Bs[arow][koff]      = rb0_c;
        *(u16x8*)&Bs[arow + 64][koff] = rb1_c;
        __syncthreads();
        ra_c = ra_n; rb0_c = rb0_n; rb1_c = rb1_n;
        if (kt < 6) {
            const int k0 = (kt + 2) * 32;
            ra_n  = *(const u16x8*)(pa + k0);
            rb0_n = *(const u16x8*)(pb0 + k0);
            rb1_n = *(const u16x8*)(pb1 + k0);
        }
        s16x8 a[2], b[4];
        const int kk = l4 * 8;
        #pragma unroll
        for (int i = 0; i < 2; ++i)
            a[i] = *(const s16x8*)&As[wr + i * 16 + l15][kk];
        #pragma unroll
        for (int j = 0; j < 4; ++j)
            b[j] = *(const s16x8*)&Bs[wc + j * 16 + l15][kk];
        #pragma unroll
        for (int i = 0; i < 2; ++i)
            #pragma unroll
            for (int j = 0; j < 4; ++j)
                acc[i][j] = __builtin_amdgcn_mfma_f32_16x16x32_bf16(a[i], b[j], acc[i][j], 0, 0, 0);
    }
    #pragma unroll
    for (int i = 0; i < 2; ++i)
        #pragma unroll
        for (int r = 0; r < 4; ++r) {
            const int m = bm + wr + i * 16 + l4 * 4 + r;
            if (m >= NNODES) continue;
            #pragma unroll
            for (int j = 0; j < 4; ++j) {
                const int n = bn + wc + j * 16 + l15;
                C[m * 256 + n] = acc[i][j][r] + bo[n];
            }
        }
}

// ---------------------------------------------------------------------------
// Fused SDDMM + softmax + SPMM. One wave per row; half-wave per edge.
// Lane w5: head w5>>2, dims (w5&3)*8..+7. Dot reduce = 2 DPP quad_perm adds.
// Col indices via scalar loads; batch-16 ping-pong (8 named slots, static
// indices) -> up to 8 independent 2x16B loads in flight per half-wave.
// ---------------------------------------------------------------------------
__global__ __launch_bounds__(256) void row_attn_k(
    const unsigned short* __restrict__ q, const unsigned short* __restrict__ kk_,
    const unsigned short* __restrict__ vv_,
    const int* __restrict__ row_start, const int* __restrict__ cols_sorted,
    unsigned short* __restrict__ ot)
{
    const int lane = threadIdx.x & 63;
    const int w5 = lane & 31;
    const int half = lane >> 5;
    const int row = __builtin_amdgcn_readfirstlane(blockIdx.x * 4 + (threadIdx.x >> 6));
    const int rs = row_start[row];
    const int re = row_start[row + 1];
    const int deg = re - rs;

    float qd[8];
    {
        const u16x8 qu = *reinterpret_cast<const u16x8*>(&q[row * 256 + w5 * 8]);
        #pragma unroll
        for (int d = 0; d < 8; ++d) qd[d] = bf2f(qu[d]);
    }
    float o[8] = {0.f, 0.f, 0.f, 0.f, 0.f, 0.f, 0.f, 0.f};
    float z = 0.f;
    const int* cp = cols_sorted + rs;

#define LP(K, V, base) do { \
    const int c0 = cp[min((base), deg - 1)]; \
    const int c1 = cp[min((base) + 1, deg - 1)]; \
    const int cn = half ? c1 : c0; \
    K = *reinterpret_cast<const u16x8*>(kk_ + cn * 256 + w5 * 8); \
    V = *reinterpret_cast<const u16x8*>(vv_ + cn * 256 + w5 * 8); \
} while (0)

#define CMP(K, V, base) do { \
    float pa_ = qd[0] * bf2f(K[0]); \
    float pb_ = qd[1] * bf2f(K[1]); \
    pa_ = fmaf(qd[2], bf2f(K[2]), pa_); \
    pb_ = fmaf(qd[3], bf2f(K[3]), pb_); \
    pa_ = fmaf(qd[4], bf2f(K[4]), pa_); \
    pb_ = fmaf(qd[5], bf2f(K[5]), pb_); \
    pa_ = fmaf(qd[6], bf2f(K[6]), pa_); \
    pb_ = fmaf(qd[7], bf2f(K[7]), pb_); \
    float p_ = pa_ + pb_; \
    p_ = dpp_xadd<0xB1>(p_); \
    p_ = dpp_xadd<0x4E>(p_); \
    const float e_ = ((base) + half < deg) ? exp2f(p_) : 0.f; \
    z += e_; \
    o[0] = fmaf(e_, bf2f(V[0]), o[0]); \
    o[1] = fmaf(e_, bf2f(V[1]), o[1]); \
    o[2] = fmaf(e_, bf2f(V[2]), o[2]); \
    o[3] = fmaf(e_, bf2f(V[3]), o[3]); \
    o[4] = fmaf(e_, bf2f(V[4]), o[4]); \
    o[5] = fmaf(e_, bf2f(V[5]), o[5]); \
    o[6] = fmaf(e_, bf2f(V[6]), o[6]); \
    o[7] = fmaf(e_, bf2f(V[7]), o[7]); \
} while (0)

    if (deg > 0) {
        u16x8 ak0, av0, ak1, av1, ak2, av2, ak3, av3;
        u16x8 bk0, bv0, bk1, bv1, bk2, bv2, bk3, bv3;
        LP(ak0, av0, 0); LP(ak1, av1, 2); LP(ak2, av2, 4); LP(ak3, av3, 6);
        for (int i0 = 0; i0 < deg; i0 += 16) {
            const bool hb2 = (i0 + 8) < deg;
            if (hb2) {
                LP(bk0, bv0, i0 + 8);  LP(bk1, bv1, i0 + 10);
                LP(bk2, bv2, i0 + 12); LP(bk3, bv3, i0 + 14);
            }
            CMP(ak0, av0, i0);     CMP(ak1, av1, i0 + 2);
            CMP(ak2, av2, i0 + 4); CMP(ak3, av3, i0 + 6);
            if (i0 + 16 < deg) {
                LP(ak0, av0, i0 + 16); LP(ak1, av1, i0 + 18);
                LP(ak2, av2, i0 + 20); LP(ak3, av3, i0 + 22);
            }
            if (hb2) {
                CMP(bk0, bv0, i0 + 8);  CMP(bk1, bv1, i0 + 10);
                CMP(bk2, bv2, i0 + 12); CMP(bk3, bv3, i0 + 14);
            }
        }
    }
#undef LP
#undef CMP

    z += __shfl_xor(z, 32);
    #pragma unroll
    for (int d = 0; d < 8; ++d) o[d] += __shfl_xor(o[d], 32);

    if (half == 0) {
        u16x8 r;
        if (deg > 0) {
            const float iz = 1.0f / z;
            #pragma unroll
            for (int d = 0; d < 8; ++d) r[d] = f2bf(o[d] * iz);
        } else {
            #pragma unroll
            for (int d = 0; d < 8; ++d) r[d] = 0;
        }
        *reinterpret_cast<u16x8*>(&ot[row * 256 + w5 * 8]) = r;
    }
}

// ---------------------------------------------------------------------------
extern "C" void kernel_launch(void* const* d_in, const int* in_sizes, int n_in,
                              void* d_out, int out_size, void* d_ws, size_t ws_size,
                              hipStream_t stream)
{
    const float* h  = (const float*)d_in[0];
    const float* Wq = (const float*)d_in[1];
    const float* bq = (const float*)d_in[2];
    const float* Wk = (const float*)d_in[3];
    const float* bk = (const float*)d_in[4];
    const float* Wv = (const float*)d_in[5];
    const float* bv = (const float*)d_in[6];
    const float* Wo = (const float*)d_in[7];
    const float* bo = (const float*)d_in[8];
    const int* rows = (const int*)d_in[9];
    const int* cols = (const int*)d_in[10];
    float* outp = (float*)d_out;

    // workspace layout (bytes), 16B-aligned; total ~54 MB
    char* ws = (char*)d_ws;
    unsigned short* q_b  = (unsigned short*)(ws + 0);          // 10,240,000
    unsigned short* k_b  = (unsigned short*)(ws + 10240000);   // 10,240,000
    unsigned short* v_b  = (unsigned short*)(ws + 20480000);   // 10,240,000
    unsigned short* ot_b = (unsigned short*)(ws + 30720000);   // 10,240,000
    unsigned short* h_b  = (unsigned short*)(ws + 40960000);   // 10,240,000
    unsigned short* wt   = (unsigned short*)(ws + 51200000);   // 524,288
    float* bp            = (float*)(ws + 51724288);            // 3,072
    int* row_start       = (int*)(ws + 51727360);              // 80,004
    int* counts          = (int*)(ws + 51807488);              // 80,000
    int* cursor          = (int*)(ws + 51887488);              // 80,000
    int* cols_sorted     = (int*)(ws + 51967488);              // 1,280,000 + pad

    hipMemsetAsync(ws + 51807488, 0, 160000, stream);          // counts + cursor

    prep_all_k<<<2277, 256, 0, stream>>>(Wq, bq, Wk, bk, Wv, bv, Wo, rows,
                                         wt, bp, counts);
    scan_hcvt_k<<<1251, 1024, 0, stream>>>(counts, row_start, h, h_b);
    qkv_scatter_k<<<SCAT_BLOCKS + 6 * MBLK, 256, 0, stream>>>(
        h_b, wt, bp, rows, cols, row_start, cursor, cols_sorted, q_b, k_b, v_b);
    row_attn_k<<<5000, 256, 0, stream>>>(q_b, k_b, v_b, row_start, cols_sorted, ot_b);
    out_mfma_k<<<dim3(313, 2), 256, 0, stream>>>(ot_b, wt, bo, outp);
}